// Round 1
// baseline (5765.277 us; speedup 1.0000x reference)
//
#include <hip/hip_runtime.h>
#include <cmath>

#define BB 16
#define LL 512
#define FEAT 512
#define NLAB 4096
#define LLAB 32
#define EE 300
#define KK 4
#define TCONV (LLAB - KK + 1)  // 29

// ---------------------------------------------------------------------------
// Kernel 0: transpose conv_w [f][e][k] -> wt2 [e][f][k]  (float4 per (e,f))
// ---------------------------------------------------------------------------
__global__ __launch_bounds__(256) void transpose_w(const float* __restrict__ conv_w,
                                                   float* __restrict__ wt2) {
    int idx = blockIdx.x * 256 + threadIdx.x;      // over E*FEAT = 153600
    if (idx >= EE * FEAT) return;
    int e = idx / FEAT, f = idx - e * FEAT;
    float4 v = reinterpret_cast<const float4*>(conv_w)[f * EE + e];
    reinterpret_cast<float4*>(wt2)[idx] = v;
}

// ---------------------------------------------------------------------------
// Kernel 1: conv1d (VALID, K=4) + bias + relu + global maxpool -> lr0 (N,FEAT)
// one block per label n; 256 threads; thread t handles channels t and t+256
// ---------------------------------------------------------------------------
__global__ __launch_bounds__(256) void conv_pool(const float* __restrict__ label_reps,
                                                 const float* __restrict__ wt2,
                                                 const float* __restrict__ conv_b,
                                                 float* __restrict__ lr0) {
    const int n = blockIdx.x;
    const int tid = threadIdx.x;
    __shared__ float lab[LLAB * EE];  // [pos][e], 9600 floats = 38.4 KB

    const float* src = label_reps + (size_t)n * (LLAB * EE);
    for (int i = tid; i < LLAB * EE; i += 256) lab[i] = src[i];
    __syncthreads();

    const int f0 = tid;
    const int f1 = tid + 256;
    float acc0[TCONV], acc1[TCONV];
#pragma unroll
    for (int t = 0; t < TCONV; ++t) { acc0[t] = 0.f; acc1[t] = 0.f; }

    const float4* w4 = reinterpret_cast<const float4*>(wt2);
    for (int e = 0; e < EE; ++e) {
        const float4 w0 = w4[e * FEAT + f0];
        const float4 w1 = w4[e * FEAT + f1];
#pragma unroll
        for (int pos = 0; pos < LLAB; ++pos) {
            const float la = lab[pos * EE + e];  // broadcast LDS read
            if (pos <= TCONV - 1) { acc0[pos] = fmaf(la, w0.x, acc0[pos]);
                                    acc1[pos] = fmaf(la, w1.x, acc1[pos]); }
            if (pos >= 1 && pos - 1 <= TCONV - 1) { acc0[pos-1] = fmaf(la, w0.y, acc0[pos-1]);
                                                    acc1[pos-1] = fmaf(la, w1.y, acc1[pos-1]); }
            if (pos >= 2 && pos - 2 <= TCONV - 1) { acc0[pos-2] = fmaf(la, w0.z, acc0[pos-2]);
                                                    acc1[pos-2] = fmaf(la, w1.z, acc1[pos-2]); }
            if (pos >= 3 && pos - 3 <= TCONV - 1) { acc0[pos-3] = fmaf(la, w0.w, acc0[pos-3]);
                                                    acc1[pos-3] = fmaf(la, w1.w, acc1[pos-3]); }
        }
    }
    float m0 = acc0[0], m1 = acc1[0];
#pragma unroll
    for (int t = 1; t < TCONV; ++t) { m0 = fmaxf(m0, acc0[t]); m1 = fmaxf(m1, acc1[t]); }
    lr0[(size_t)n * FEAT + f0] = fmaxf(m0 + conv_b[f0], 0.f);
    lr0[(size_t)n * FEAT + f1] = fmaxf(m1 + conv_b[f1], 0.f);
}

// ---------------------------------------------------------------------------
// Kernel 2: lr = lr0 @ lin_w^T + lin_b   (M=4096, N=512, K=512)
// 64x64 tiles, Ktile=16, 256 threads, 4x4 per thread
// ---------------------------------------------------------------------------
__global__ __launch_bounds__(256) void linear_kernel(const float* __restrict__ lr0,
                                                     const float* __restrict__ lin_w,
                                                     const float* __restrict__ lin_b,
                                                     float* __restrict__ lr) {
    const int m0 = blockIdx.x * 64;
    const int i0 = blockIdx.y * 64;
    const int tid = threadIdx.x;
    const int tx = tid & 15;   // -> i
    const int ty = tid >> 4;   // -> m
    __shared__ float As[16][65];
    __shared__ float Bs[16][65];
    float acc[4][4] = {};

    for (int k0 = 0; k0 < 512; k0 += 16) {
        const int k = tid & 15, m = tid >> 4;  // m 0..15
#pragma unroll
        for (int p = 0; p < 4; ++p)
            As[k][m + p*16] = lr0[(size_t)(m0 + m + p*16) * 512 + k0 + k];
#pragma unroll
        for (int p = 0; p < 4; ++p)
            Bs[k][m + p*16] = lin_w[(size_t)(i0 + m + p*16) * 512 + k0 + k];
        __syncthreads();
#pragma unroll
        for (int kk = 0; kk < 16; ++kk) {
            float a[4], b[4];
#pragma unroll
            for (int r = 0; r < 4; ++r) { a[r] = As[kk][ty*4 + r]; b[r] = Bs[kk][tx*4 + r]; }
#pragma unroll
            for (int ar = 0; ar < 4; ++ar)
#pragma unroll
                for (int br = 0; br < 4; ++br)
                    acc[ar][br] = fmaf(a[ar], b[br], acc[ar][br]);
        }
        __syncthreads();
    }
#pragma unroll
    for (int ar = 0; ar < 4; ++ar) {
        const int row = m0 + ty*4 + ar;
        const int col = i0 + tx*4;
        float4 v;
        v.x = acc[ar][0] + lin_b[col + 0];
        v.y = acc[ar][1] + lin_b[col + 1];
        v.z = acc[ar][2] + lin_b[col + 2];
        v.w = acc[ar][3] + lin_b[col + 3];
        *reinterpret_cast<float4*>(&lr[(size_t)row * 512 + col]) = v;
    }
}

// ---------------------------------------------------------------------------
// Kernel 3: fused attention  out[b,n,f] = softmax_l(x[b,l,:].lr[n,:]) @ x[b,:,f]
// flash-style online softmax; block = 32 n-rows of one batch b; 256 threads
// thread (tx 0..31, ty 0..7): S-tile 4n x 4l, out-tile 4n x (4 fchunks x 4f)
// ---------------------------------------------------------------------------
#define NT 32
#define LT 128
#define KT 32

__global__ __launch_bounds__(256) void attention_kernel(const float* __restrict__ x,
                                                        const float* __restrict__ lr,
                                                        float* __restrict__ out) {
    const int b  = blockIdx.y;
    const int n0 = blockIdx.x * NT;
    const int tid = threadIdx.x;
    const int tx = tid & 31;
    const int ty = tid >> 5;

    __shared__ __align__(16) float As[KT][NT + 1];   // lr tile [k(f)][n]
    __shared__ __align__(16) float Xs[KT][LT + 4];   // x tile  [k][l] / [l'][f]
    __shared__ __align__(16) float Ps[NT][LT + 4];   // p tile  [n][l]

    float out_acc[4][4][4];  // [fchunk][nj][fi]
#pragma unroll
    for (int c = 0; c < 4; ++c)
#pragma unroll
        for (int j = 0; j < 4; ++j)
#pragma unroll
            for (int i = 0; i < 4; ++i) out_acc[c][j][i] = 0.f;
    float m_run[4] = {-INFINITY, -INFINITY, -INFINITY, -INFINITY};
    float d_run[4] = {0.f, 0.f, 0.f, 0.f};

    const float* xb = x + (size_t)b * (LL * FEAT);

    for (int lt = 0; lt < LL; lt += LT) {
        // ---- S phase: s[n][l] = sum_f lr[n][f] * x[l][f] ----
        float s_acc[4][4] = {};
        for (int k0 = 0; k0 < FEAT; k0 += KT) {
            const int k = tid & 31, rr = tid >> 5;  // rr 0..7
#pragma unroll
            for (int p = 0; p < 4; ++p)
                As[k][rr + p*8] = lr[(size_t)(n0 + rr + p*8) * FEAT + k0 + k];
#pragma unroll
            for (int p = 0; p < 16; ++p)
                Xs[k][rr + p*8] = xb[(size_t)(lt + rr + p*8) * FEAT + k0 + k];
            __syncthreads();
#pragma unroll
            for (int kk = 0; kk < KT; ++kk) {
                float a[4];
#pragma unroll
                for (int j = 0; j < 4; ++j) a[j] = As[kk][ty*4 + j];
                const float4 bv = *reinterpret_cast<const float4*>(&Xs[kk][tx*4]);
#pragma unroll
                for (int j = 0; j < 4; ++j) {
                    s_acc[j][0] = fmaf(a[j], bv.x, s_acc[j][0]);
                    s_acc[j][1] = fmaf(a[j], bv.y, s_acc[j][1]);
                    s_acc[j][2] = fmaf(a[j], bv.z, s_acc[j][2]);
                    s_acc[j][3] = fmaf(a[j], bv.w, s_acc[j][3]);
                }
            }
            __syncthreads();
        }
        // ---- online softmax update (state replicated across 32-lane tx group) ----
#pragma unroll
        for (int j = 0; j < 4; ++j) {
            float tmax = fmaxf(fmaxf(s_acc[j][0], s_acc[j][1]),
                               fmaxf(s_acc[j][2], s_acc[j][3]));
            for (int o = 16; o >= 1; o >>= 1) tmax = fmaxf(tmax, __shfl_xor(tmax, o));
            const float mnew  = fmaxf(m_run[j], tmax);
            const float alpha = expf(m_run[j] - mnew);  // first tile: exp(-inf)=0
            float p0 = expf(s_acc[j][0] - mnew);
            float p1 = expf(s_acc[j][1] - mnew);
            float p2 = expf(s_acc[j][2] - mnew);
            float p3 = expf(s_acc[j][3] - mnew);
            float psum = p0 + p1 + p2 + p3;
            for (int o = 16; o >= 1; o >>= 1) psum += __shfl_xor(psum, o);
            d_run[j] = d_run[j] * alpha + psum;
            m_run[j] = mnew;
#pragma unroll
            for (int c = 0; c < 4; ++c)
#pragma unroll
                for (int i = 0; i < 4; ++i) out_acc[c][j][i] *= alpha;
            float4 pv; pv.x = p0; pv.y = p1; pv.z = p2; pv.w = p3;
            *reinterpret_cast<float4*>(&Ps[ty*4 + j][tx*4]) = pv;
        }
        __syncthreads();
        // ---- PV phase: out[n][f] += sum_{l in tile} p[n][l] * x[l][f] ----
#pragma unroll
        for (int fc = 0; fc < 4; ++fc) {
            for (int kk = 0; kk < LT; kk += KT) {
#pragma unroll
                for (int q = 0; q < 16; ++q) {
                    int idx = q * 256 + tid;
                    int fp = idx & 127, lp = idx >> 7;
                    Xs[lp][fp] = xb[(size_t)(lt + kk + lp) * FEAT + fc*128 + fp];
                }
                __syncthreads();
#pragma unroll
                for (int k = 0; k < KT; ++k) {
                    float a[4];
#pragma unroll
                    for (int j = 0; j < 4; ++j) a[j] = Ps[ty*4 + j][kk + k];
                    const float4 bv = *reinterpret_cast<const float4*>(&Xs[k][tx*4]);
#pragma unroll
                    for (int j = 0; j < 4; ++j) {
                        out_acc[fc][j][0] = fmaf(a[j], bv.x, out_acc[fc][j][0]);
                        out_acc[fc][j][1] = fmaf(a[j], bv.y, out_acc[fc][j][1]);
                        out_acc[fc][j][2] = fmaf(a[j], bv.z, out_acc[fc][j][2]);
                        out_acc[fc][j][3] = fmaf(a[j], bv.w, out_acc[fc][j][3]);
                    }
                }
                __syncthreads();
            }
        }
    }
    // ---- epilogue: normalize and store ----
#pragma unroll
    for (int j = 0; j < 4; ++j) {
        const float rinv = 1.0f / d_run[j];
        const int n = n0 + ty*4 + j;
#pragma unroll
        for (int fc = 0; fc < 4; ++fc) {
            float4 v;
            v.x = out_acc[fc][j][0] * rinv;
            v.y = out_acc[fc][j][1] * rinv;
            v.z = out_acc[fc][j][2] * rinv;
            v.w = out_acc[fc][j][3] * rinv;
            *reinterpret_cast<float4*>(&out[((size_t)b * NLAB + n) * FEAT + fc*128 + tx*4]) = v;
        }
    }
}

// ---------------------------------------------------------------------------
extern "C" void kernel_launch(void* const* d_in, const int* in_sizes, int n_in,
                              void* d_out, int out_size, void* d_ws, size_t ws_size,
                              hipStream_t stream) {
    const float* x          = (const float*)d_in[0];  // (16,512,512)
    const float* label_reps = (const float*)d_in[1];  // (4096,32,300)
    const float* conv_w     = (const float*)d_in[2];  // (512,300,4)
    const float* conv_b     = (const float*)d_in[3];  // (512,)
    const float* lin_w      = (const float*)d_in[4];  // (512,512)
    const float* lin_b      = (const float*)d_in[5];  // (512,)
    float* out = (float*)d_out;

    float* wt2 = (float*)d_ws;               // 614400 floats (2.4 MB)
    float* lr0 = wt2 + (size_t)EE*FEAT*KK;   // 4096*512 floats (8 MB)
    float* lrb = lr0 + (size_t)NLAB*FEAT;    // 4096*512 floats (8 MB)

    transpose_w<<<dim3(600), dim3(256), 0, stream>>>(conv_w, wt2);
    conv_pool<<<dim3(NLAB), dim3(256), 0, stream>>>(label_reps, wt2, conv_b, lr0);
    linear_kernel<<<dim3(64, 8), dim3(256), 0, stream>>>(lr0, lin_w, lin_b, lrb);
    attention_kernel<<<dim3(NLAB / NT, BB), dim3(256), 0, stream>>>(x, lrb, out);
}

// Round 3
// 2673.022 us; speedup vs baseline: 2.1568x; 2.1568x over previous
//
#include <hip/hip_runtime.h>
#include <cmath>

#define BB 16
#define LL 512
#define FEAT 512
#define NLAB 4096
#define LLAB 32
#define EE 300
#define KK 4
#define TCONV (LLAB - KK + 1)  // 29

typedef __bf16 bf16x8 __attribute__((ext_vector_type(8)));
typedef float f32x4 __attribute__((ext_vector_type(4)));

// ---------------------------------------------------------------------------
// Kernel 0: transpose conv_w [f][e][k] -> wt2 [e][f][k]  (float4 per (e,f))
// ---------------------------------------------------------------------------
__global__ __launch_bounds__(256) void transpose_w(const float* __restrict__ conv_w,
                                                   float* __restrict__ wt2) {
    int idx = blockIdx.x * 256 + threadIdx.x;      // over E*FEAT = 153600
    if (idx >= EE * FEAT) return;
    int e = idx / FEAT, f = idx - e * FEAT;
    float4 v = reinterpret_cast<const float4*>(conv_w)[f * EE + e];
    reinterpret_cast<float4*>(wt2)[idx] = v;
}

// ---------------------------------------------------------------------------
// Kernel 1: conv1d (VALID, K=4) + bias + relu + global maxpool -> lr0 (N,FEAT)
// ---------------------------------------------------------------------------
__global__ __launch_bounds__(256) void conv_pool(const float* __restrict__ label_reps,
                                                 const float* __restrict__ wt2,
                                                 const float* __restrict__ conv_b,
                                                 float* __restrict__ lr0) {
    const int n = blockIdx.x;
    const int tid = threadIdx.x;
    __shared__ float lab[LLAB * EE];  // [pos][e]

    const float* src = label_reps + (size_t)n * (LLAB * EE);
    for (int i = tid; i < LLAB * EE; i += 256) lab[i] = src[i];
    __syncthreads();

    const int f0 = tid;
    const int f1 = tid + 256;
    float acc0[TCONV], acc1[TCONV];
#pragma unroll
    for (int t = 0; t < TCONV; ++t) { acc0[t] = 0.f; acc1[t] = 0.f; }

    const float4* w4 = reinterpret_cast<const float4*>(wt2);
    for (int e = 0; e < EE; ++e) {
        const float4 w0 = w4[e * FEAT + f0];
        const float4 w1 = w4[e * FEAT + f1];
#pragma unroll
        for (int pos = 0; pos < LLAB; ++pos) {
            const float la = lab[pos * EE + e];
            if (pos <= TCONV - 1) { acc0[pos] = fmaf(la, w0.x, acc0[pos]);
                                    acc1[pos] = fmaf(la, w1.x, acc1[pos]); }
            if (pos >= 1 && pos - 1 <= TCONV - 1) { acc0[pos-1] = fmaf(la, w0.y, acc0[pos-1]);
                                                    acc1[pos-1] = fmaf(la, w1.y, acc1[pos-1]); }
            if (pos >= 2 && pos - 2 <= TCONV - 1) { acc0[pos-2] = fmaf(la, w0.z, acc0[pos-2]);
                                                    acc1[pos-2] = fmaf(la, w1.z, acc1[pos-2]); }
            if (pos >= 3 && pos - 3 <= TCONV - 1) { acc0[pos-3] = fmaf(la, w0.w, acc0[pos-3]);
                                                    acc1[pos-3] = fmaf(la, w1.w, acc1[pos-3]); }
        }
    }
    float m0 = acc0[0], m1 = acc1[0];
#pragma unroll
    for (int t = 1; t < TCONV; ++t) { m0 = fmaxf(m0, acc0[t]); m1 = fmaxf(m1, acc1[t]); }
    lr0[(size_t)n * FEAT + f0] = fmaxf(m0 + conv_b[f0], 0.f);
    lr0[(size_t)n * FEAT + f1] = fmaxf(m1 + conv_b[f1], 0.f);
}

// ---------------------------------------------------------------------------
// Kernel 2: lr = lr0 @ lin_w^T + lin_b, epilogue split -> lr_hi/lr_lo (bf16)
// ---------------------------------------------------------------------------
__global__ __launch_bounds__(256) void linear_kernel(const float* __restrict__ lr0,
                                                     const float* __restrict__ lin_w,
                                                     const float* __restrict__ lin_b,
                                                     __bf16* __restrict__ lr_hi,
                                                     __bf16* __restrict__ lr_lo) {
    const int m0 = blockIdx.x * 64;
    const int i0 = blockIdx.y * 64;
    const int tid = threadIdx.x;
    const int tx = tid & 15;
    const int ty = tid >> 4;
    __shared__ float As[16][65];
    __shared__ float Bs[16][65];
    float acc[4][4] = {};

    for (int k0 = 0; k0 < 512; k0 += 16) {
        const int k = tid & 15, m = tid >> 4;
#pragma unroll
        for (int p = 0; p < 4; ++p)
            As[k][m + p*16] = lr0[(size_t)(m0 + m + p*16) * 512 + k0 + k];
#pragma unroll
        for (int p = 0; p < 4; ++p)
            Bs[k][m + p*16] = lin_w[(size_t)(i0 + m + p*16) * 512 + k0 + k];
        __syncthreads();
#pragma unroll
        for (int kk = 0; kk < 16; ++kk) {
            float a[4], b[4];
#pragma unroll
            for (int r = 0; r < 4; ++r) { a[r] = As[kk][ty*4 + r]; b[r] = Bs[kk][tx*4 + r]; }
#pragma unroll
            for (int ar = 0; ar < 4; ++ar)
#pragma unroll
                for (int br = 0; br < 4; ++br)
                    acc[ar][br] = fmaf(a[ar], b[br], acc[ar][br]);
        }
        __syncthreads();
    }
#pragma unroll
    for (int ar = 0; ar < 4; ++ar) {
        const int row = m0 + ty*4 + ar;
        const int col = i0 + tx*4;
#pragma unroll
        for (int br = 0; br < 4; ++br) {
            float v = acc[ar][br] + lin_b[col + br];
            __bf16 h = (__bf16)v;
            lr_hi[(size_t)row * 512 + col + br] = h;
            lr_lo[(size_t)row * 512 + col + br] = (__bf16)(v - (float)h);
        }
    }
}

// ---------------------------------------------------------------------------
// Kernel 2b: split x -> x_hi/x_lo (bf16 [b][l][f]) + xT (bf16 [b][f][l])
// 64x64 tiles per block
// ---------------------------------------------------------------------------
__global__ __launch_bounds__(256) void split_x(const float* __restrict__ x,
                                               __bf16* __restrict__ x_hi,
                                               __bf16* __restrict__ x_lo,
                                               __bf16* __restrict__ xT) {
    const int b  = blockIdx.z;
    const int l0 = blockIdx.y * 64;
    const int f0 = blockIdx.x * 64;
    const int tid = threadIdx.x;
    __shared__ __bf16 tile[64][65];
    const int j = tid & 63;
#pragma unroll
    for (int s = 0; s < 16; ++s) {
        const int rr = (tid >> 6) + s * 4;
        const size_t o = ((size_t)(b * 512 + l0 + rr)) * 512 + f0 + j;
        float v = x[o];
        __bf16 h = (__bf16)v;
        x_hi[o] = h;
        x_lo[o] = (__bf16)(v - (float)h);
        tile[rr][j] = h;
    }
    __syncthreads();
#pragma unroll
    for (int s = 0; s < 16; ++s) {
        const int ff = (tid >> 6) + s * 4;
        xT[((size_t)(b * 512 + f0 + ff)) * 512 + l0 + j] = tile[j][ff];
    }
}

// ---------------------------------------------------------------------------
// Kernel 3: MFMA flash attention.
// Block: 16 labels (n) x one batch b, 4 waves. L-tile = 64 (16 l per wave).
// S = lr.x^T via split-bf16 3-pass MFMA; softmax online; PV single bf16 MFMA.
// Frag layouts (verified m89/m91): A/B row=lane&15, k=quad*8+j;
//                                  D col=lane&15, row=quad*4+reg.
// ---------------------------------------------------------------------------
#define LT 64

__global__ __launch_bounds__(256) void attention_mfma(const __bf16* __restrict__ x_hi,
                                                      const __bf16* __restrict__ x_lo,
                                                      const __bf16* __restrict__ xT,
                                                      const __bf16* __restrict__ lr_hi,
                                                      const __bf16* __restrict__ lr_lo,
                                                      float* __restrict__ out) {
    const int b  = blockIdx.y;
    const int n0 = blockIdx.x * 16;
    const int tid  = threadIdx.x;
    const int wave = tid >> 6;
    const int lane = tid & 63;
    const int quad = lane >> 4;
    const int l16  = lane & 15;

    __shared__ float m_run[16];
    __shared__ float d_run[16];
    __shared__ float wavemax[4][16];
    __shared__ float wavesum[4][16];
    __shared__ float Ps[16][LT + 4];   // P fp32, [n][l-in-tile]

    if (tid < 16) { m_run[tid] = -INFINITY; d_run[tid] = 0.f; }
    __syncthreads();

    f32x4 oacc[8];                      // f = wave*128 + fs*16 + l16
#pragma unroll
    for (int fs = 0; fs < 8; ++fs) oacc[fs] = (f32x4){0.f, 0.f, 0.f, 0.f};

    const __bf16* lrh = lr_hi + (size_t)(n0 + l16) * FEAT + quad * 8;
    const __bf16* lrl = lr_lo + (size_t)(n0 + l16) * FEAT + quad * 8;

    for (int lt = 0; lt < LL; lt += LT) {
        const int lbase = lt + wave * 16;
        // ---- S phase: S[n][l16] over this wave's 16 l's ----
        f32x4 s = (f32x4){0.f, 0.f, 0.f, 0.f};
        const __bf16* xh = x_hi + ((size_t)(b * LL + lbase + l16)) * FEAT + quad * 8;
        const __bf16* xl = x_lo + ((size_t)(b * LL + lbase + l16)) * FEAT + quad * 8;
#pragma unroll
        for (int k0 = 0; k0 < FEAT; k0 += 32) {
            const bf16x8 ah = *(const bf16x8*)(lrh + k0);
            const bf16x8 al = *(const bf16x8*)(lrl + k0);
            const bf16x8 bh = *(const bf16x8*)(xh + k0);
            const bf16x8 bl = *(const bf16x8*)(xl + k0);
            s = __builtin_amdgcn_mfma_f32_16x16x32_bf16(ah, bh, s, 0, 0, 0);
            s = __builtin_amdgcn_mfma_f32_16x16x32_bf16(ah, bl, s, 0, 0, 0);
            s = __builtin_amdgcn_mfma_f32_16x16x32_bf16(al, bh, s, 0, 0, 0);
        }
        // ---- row max within wave's 16-l subtile (over lanes l16) ----
        float rmax[4];
#pragma unroll
        for (int r = 0; r < 4; ++r) {
            float v = s[r];
            v = fmaxf(v, __shfl_xor(v, 1));
            v = fmaxf(v, __shfl_xor(v, 2));
            v = fmaxf(v, __shfl_xor(v, 4));
            v = fmaxf(v, __shfl_xor(v, 8));
            rmax[r] = v;
        }
        if (l16 == 0) {
#pragma unroll
            for (int r = 0; r < 4; ++r) wavemax[wave][quad * 4 + r] = rmax[r];
        }
        __syncthreads();                                   // barrier 1
        // ---- new running max / alpha / P / partial sums ----
        float mnew[4], alpha[4], p[4];
#pragma unroll
        for (int r = 0; r < 4; ++r) {
            const int n = quad * 4 + r;
            float tm = fmaxf(fmaxf(wavemax[0][n], wavemax[1][n]),
                             fmaxf(wavemax[2][n], wavemax[3][n]));
            float mo = m_run[n];
            mnew[r]  = fmaxf(mo, tm);
            alpha[r] = __expf(mo - mnew[r]);
            p[r]     = __expf(s[r] - mnew[r]);
            float ps = p[r];
            ps += __shfl_xor(ps, 1);
            ps += __shfl_xor(ps, 2);
            ps += __shfl_xor(ps, 4);
            ps += __shfl_xor(ps, 8);
            if (l16 == 0) wavesum[wave][n] = ps;
            Ps[n][wave * 16 + l16] = p[r];
        }
        __syncthreads();                                   // barrier 2
        if (wave == 0 && l16 == 0) {
#pragma unroll
            for (int r = 0; r < 4; ++r) {
                const int n = quad * 4 + r;
                float sum4 = wavesum[0][n] + wavesum[1][n] + wavesum[2][n] + wavesum[3][n];
                d_run[n] = d_run[n] * alpha[r] + sum4;
                m_run[n] = mnew[r];
            }
        }
        __syncthreads();                                   // barrier 3
        // ---- PV phase: rescale acc, then out += P(16xLT) . x(LTx512) ----
#pragma unroll
        for (int fs = 0; fs < 8; ++fs)
#pragma unroll
            for (int r = 0; r < 4; ++r) oacc[fs][r] *= alpha[r];

        bf16x8 ap[2];
#pragma unroll
        for (int kb = 0; kb < 2; ++kb) {
            const float* srcp = &Ps[l16][kb * 32 + quad * 8];
            const float4 v0 = *(const float4*)(srcp);
            const float4 v1 = *(const float4*)(srcp + 4);
            bf16x8 t;
            t[0] = (__bf16)v0.x; t[1] = (__bf16)v0.y; t[2] = (__bf16)v0.z; t[3] = (__bf16)v0.w;
            t[4] = (__bf16)v1.x; t[5] = (__bf16)v1.y; t[6] = (__bf16)v1.z; t[7] = (__bf16)v1.w;
            ap[kb] = t;
        }
        const __bf16* xtb = xT + ((size_t)(b * FEAT + wave * 128 + l16)) * LL + lt + quad * 8;
#pragma unroll
        for (int fs = 0; fs < 8; ++fs) {
#pragma unroll
            for (int kb = 0; kb < 2; ++kb) {
                const bf16x8 bfrag = *(const bf16x8*)(xtb + (size_t)fs * 16 * LL + kb * 32);
                oacc[fs] = __builtin_amdgcn_mfma_f32_16x16x32_bf16(ap[kb], bfrag, oacc[fs], 0, 0, 0);
            }
        }
        // Ps/wavemax/wavesum reused next iter only after its barrier1/2 — safe.
    }
    // ---- epilogue: normalize, store ----
    float dinv[4];
#pragma unroll
    for (int r = 0; r < 4; ++r) dinv[r] = 1.0f / d_run[quad * 4 + r];
#pragma unroll
    for (int fs = 0; fs < 8; ++fs) {
#pragma unroll
        for (int r = 0; r < 4; ++r) {
            const int n = n0 + quad * 4 + r;
            const int f = wave * 128 + fs * 16 + l16;
            out[((size_t)(b * NLAB + n)) * FEAT + f] = oacc[fs][r] * dinv[r];
        }
    }
}

// ---------------------------------------------------------------------------
// Workspace layout (floats). x_hi/x_lo/xT are 16*512*512 = 4,194,304 bf16
// = 2,097,152 float-slots EACH (round-1 bug: halved elements, not bytes).
// Aliasing: wt2+lr0 are dead after linear_kernel completes (stream order),
// so the x-split buffers reuse that region. Peak = 8,388,608 f = 32 MB.
//
//   [0        .. 1048576)  lr_hi   (4096*512 bf16)
//   [1048576  .. 2097152)  lr_lo   (4096*512 bf16)
//   [2097152  .. 2711552)  wt2     (fp32, dead after conv_pool)
//   [2711552  .. 4808704)  lr0     (fp32, dead after linear_kernel)
//   [2097152  .. 4194304)  x_hi    (written by split_x, after linear)
//   [4194304  .. 6291456)  x_lo
//   [6291456  .. 8388608)  xT
// ---------------------------------------------------------------------------
extern "C" void kernel_launch(void* const* d_in, const int* in_sizes, int n_in,
                              void* d_out, int out_size, void* d_ws, size_t ws_size,
                              hipStream_t stream) {
    const float* x          = (const float*)d_in[0];  // (16,512,512)
    const float* label_reps = (const float*)d_in[1];  // (4096,32,300)
    const float* conv_w     = (const float*)d_in[2];  // (512,300,4)
    const float* conv_b     = (const float*)d_in[3];  // (512,)
    const float* lin_w      = (const float*)d_in[4];  // (512,512)
    const float* lin_b      = (const float*)d_in[5];  // (512,)
    float* out = (float*)d_out;

    float* wsf = (float*)d_ws;
    __bf16* lr_hi = (__bf16*)(wsf);
    __bf16* lr_lo = (__bf16*)(wsf + 1048576);
    float*  wt2   = wsf + 2097152;
    float*  lr0   = wsf + 2711552;
    __bf16* x_hi  = (__bf16*)(wsf + 2097152);   // aliases wt2/lr0 (dead by then)
    __bf16* x_lo  = (__bf16*)(wsf + 4194304);
    __bf16* xT    = (__bf16*)(wsf + 6291456);

    transpose_w<<<dim3(600), dim3(256), 0, stream>>>(conv_w, wt2);
    conv_pool<<<dim3(NLAB), dim3(256), 0, stream>>>(label_reps, wt2, conv_b, lr0);
    linear_kernel<<<dim3(64, 8), dim3(256), 0, stream>>>(lr0, lin_w, lin_b, lr_hi, lr_lo);
    split_x<<<dim3(8, 8, 16), dim3(256), 0, stream>>>(x, x_hi, x_lo, xT);
    attention_mfma<<<dim3(NLAB / 16, BB), dim3(256), 0, stream>>>(x_hi, x_lo, xT, lr_hi, lr_lo, out);
}

// Round 4
// 2027.064 us; speedup vs baseline: 2.8442x; 1.3187x over previous
//
#include <hip/hip_runtime.h>
#include <cmath>

#define BB 16
#define LL 512
#define FEAT 512
#define NLAB 4096
#define LLAB 32
#define EE 300
#define KK 4
#define TCONV (LLAB - KK + 1)  // 29

typedef __bf16 bf16x8 __attribute__((ext_vector_type(8)));
typedef __bf16 bf16x4 __attribute__((ext_vector_type(4)));
typedef float f32x4 __attribute__((ext_vector_type(4)));

// ---------------------------------------------------------------------------
// Kernel 0: weight prep. conv_w [f][e][k] fp32 -> wBt_hi/lo bf16 [16][128][320]
// col c = k*32 + fj  (f = fb*32 + fj), e padded 300->320 with zeros.
// ---------------------------------------------------------------------------
__global__ __launch_bounds__(256) void wprep(const float* __restrict__ conv_w,
                                             __bf16* __restrict__ wBt_hi,
                                             __bf16* __restrict__ wBt_lo) {
    const int col = blockIdx.x;            // 0..2047 = fb*128 + c
    const int fb = col >> 7, c = col & 127;
    const int f = fb * 32 + (c & 31), k = c >> 5;
    for (int e = threadIdx.x; e < 320; e += 256) {
        float v = (e < 300) ? conv_w[((size_t)f * 300 + e) * 4 + k] : 0.f;
        __bf16 h = (__bf16)v;
        wBt_hi[(size_t)col * 320 + e] = h;
        wBt_lo[(size_t)col * 320 + e] = (__bf16)(v - (float)h);
    }
}

// ---------------------------------------------------------------------------
// Kernel 1: implicit-GEMM conv + shift-add(k) + bias + relu + maxpool -> lr0
// Grid: (16 f-blocks, 1024 n-blocks). Block: 256 thr = 4 waves.
// Block tile: 128 rows (4 labels x 32 pos) x 128 cols (4 k x 32 f), K=320.
// Wave w owns rows [w*32, w*32+32) = label w. Split-bf16 3-pass MFMA.
// Frag layouts (verified m89/m91): A/B row/col=lane&15, k=quad*8+j;
//                                  D col=lane&15, row=quad*4+reg.
// ---------------------------------------------------------------------------
__global__ __launch_bounds__(256) void conv_mfma(const float* __restrict__ label_reps,
                                                 const __bf16* __restrict__ wBt_hi,
                                                 const __bf16* __restrict__ wBt_lo,
                                                 const float* __restrict__ conv_b,
                                                 float* __restrict__ lr0) {
    const int fb = blockIdx.x;   // 0..15
    const int nb = blockIdx.y;   // 0..1023
    const int tid = threadIdx.x;
    const int wave = tid >> 6;
    const int lane = tid & 63;
    const int quad = lane >> 4;
    const int l16  = lane & 15;

    // stride 40 bf16 (80 B): 16B-aligned rows, frag reads 2-way banks (free)
    __shared__ __align__(16) __bf16 Ah[128][40];
    __shared__ __align__(16) __bf16 Al[128][40];
    __shared__ __align__(16) __bf16 Bh[128][40];
    __shared__ __align__(16) __bf16 Bl[128][40];

    f32x4 acc[2][8];   // [ri][cj]; cj: k = cj>>1, fhalf = cj&1
#pragma unroll
    for (int ri = 0; ri < 2; ++ri)
#pragma unroll
        for (int cj = 0; cj < 8; ++cj) acc[ri][cj] = (f32x4){0.f, 0.f, 0.f, 0.f};

    for (int e0 = 0; e0 < 320; e0 += 32) {
        // ---- stage A: 128 rows x 32 e, fp32 -> hi/lo bf16 ----
        {
            const int r  = tid >> 1;
            const int ep = (tid & 1) * 16;
            const float* src = label_reps + (size_t)(nb * 128 + r) * 300 + e0 + ep;
            if (e0 < 288) {
#pragma unroll
                for (int j4 = 0; j4 < 4; ++j4) {
                    const float4 v = *(const float4*)(src + j4 * 4);
                    bf16x4 h, l;
                    h[0] = (__bf16)v.x; l[0] = (__bf16)(v.x - (float)h[0]);
                    h[1] = (__bf16)v.y; l[1] = (__bf16)(v.y - (float)h[1]);
                    h[2] = (__bf16)v.z; l[2] = (__bf16)(v.z - (float)h[2]);
                    h[3] = (__bf16)v.w; l[3] = (__bf16)(v.w - (float)h[3]);
                    *(bf16x4*)&Ah[r][ep + j4 * 4] = h;
                    *(bf16x4*)&Al[r][ep + j4 * 4] = l;
                }
            } else {  // last K-tile: e 288..319, valid < 300
#pragma unroll
                for (int j4 = 0; j4 < 4; ++j4) {
                    float vv[4];
#pragma unroll
                    for (int u = 0; u < 4; ++u) {
                        const int e = e0 + ep + j4 * 4 + u;
                        vv[u] = (e < 300) ? src[j4 * 4 + u] : 0.f;
                    }
                    bf16x4 h, l;
#pragma unroll
                    for (int u = 0; u < 4; ++u) {
                        h[u] = (__bf16)vv[u]; l[u] = (__bf16)(vv[u] - (float)h[u]);
                    }
                    *(bf16x4*)&Ah[r][ep + j4 * 4] = h;
                    *(bf16x4*)&Al[r][ep + j4 * 4] = l;
                }
            }
        }
        // ---- stage B: 128 cols x 32 e (pre-split bf16) ----
        {
            const int c = tid & 127;
            const __bf16* wsrc = ((tid >> 7) ? wBt_lo : wBt_hi) +
                                 ((size_t)fb * 128 + c) * 320 + e0;
            __bf16* dst = (tid >> 7) ? &Bl[c][0] : &Bh[c][0];
#pragma unroll
            for (int j = 0; j < 4; ++j)
                *(bf16x8*)(dst + j * 8) = *(const bf16x8*)(wsrc + j * 8);
        }
        __syncthreads();
        // ---- MFMA: 2 ri x 8 cj x 3 passes ----
        bf16x8 ah[2], al[2];
#pragma unroll
        for (int ri = 0; ri < 2; ++ri) {
            ah[ri] = *(const bf16x8*)&Ah[wave * 32 + ri * 16 + l16][quad * 8];
            al[ri] = *(const bf16x8*)&Al[wave * 32 + ri * 16 + l16][quad * 8];
        }
#pragma unroll
        for (int cj = 0; cj < 8; ++cj) {
            const bf16x8 bh = *(const bf16x8*)&Bh[cj * 16 + l16][quad * 8];
            const bf16x8 bl = *(const bf16x8*)&Bl[cj * 16 + l16][quad * 8];
#pragma unroll
            for (int ri = 0; ri < 2; ++ri) {
                acc[ri][cj] = __builtin_amdgcn_mfma_f32_16x16x32_bf16(ah[ri], bh, acc[ri][cj], 0, 0, 0);
                acc[ri][cj] = __builtin_amdgcn_mfma_f32_16x16x32_bf16(ah[ri], bl, acc[ri][cj], 0, 0, 0);
                acc[ri][cj] = __builtin_amdgcn_mfma_f32_16x16x32_bf16(al[ri], bh, acc[ri][cj], 0, 0, 0);
            }
        }
        __syncthreads();
    }
    // ---- epilogue: h[t][f] = sum_k C[t+k][k], then max_t, +bias, relu ----
    // lane holds rows r with ((r>>2)&3)==quad (r = ri*16 + quad*4 + reg);
    // cross-quad completion via shfl_xor(16|32).
    const int label = nb * 4 + wave;
#pragma unroll
    for (int fh = 0; fh < 2; ++fh) {
        float m = -INFINITY;
#pragma unroll
        for (int t = 0; t < TCONV; ++t) {
            float loc = 0.f;
#pragma unroll
            for (int k = 0; k < KK; ++k) {
                const int r = t + k;                 // 0..31
                const float v = acc[r >> 4][k * 2 + fh][r & 3];
                loc += (((r >> 2) & 3) == quad) ? v : 0.f;
            }
            loc += __shfl_xor(loc, 16);
            loc += __shfl_xor(loc, 32);
            m = fmaxf(m, loc);
        }
        if (quad == 0) {
            const int f = fb * 32 + fh * 16 + l16;
            lr0[(size_t)label * FEAT + f] = fmaxf(m + conv_b[f], 0.f);
        }
    }
}

// ---------------------------------------------------------------------------
// Kernel 2: lr = lr0 @ lin_w^T + lin_b, epilogue split -> lr_hi/lr_lo (bf16)
// ---------------------------------------------------------------------------
__global__ __launch_bounds__(256) void linear_kernel(const float* __restrict__ lr0,
                                                     const float* __restrict__ lin_w,
                                                     const float* __restrict__ lin_b,
                                                     __bf16* __restrict__ lr_hi,
                                                     __bf16* __restrict__ lr_lo) {
    const int m0 = blockIdx.x * 64;
    const int i0 = blockIdx.y * 64;
    const int tid = threadIdx.x;
    const int tx = tid & 15;
    const int ty = tid >> 4;
    __shared__ float As[16][65];
    __shared__ float Bs[16][65];
    float acc[4][4] = {};

    for (int k0 = 0; k0 < 512; k0 += 16) {
        const int k = tid & 15, m = tid >> 4;
#pragma unroll
        for (int p = 0; p < 4; ++p)
            As[k][m + p*16] = lr0[(size_t)(m0 + m + p*16) * 512 + k0 + k];
#pragma unroll
        for (int p = 0; p < 4; ++p)
            Bs[k][m + p*16] = lin_w[(size_t)(i0 + m + p*16) * 512 + k0 + k];
        __syncthreads();
#pragma unroll
        for (int kk = 0; kk < 16; ++kk) {
            float a[4], b[4];
#pragma unroll
            for (int r = 0; r < 4; ++r) { a[r] = As[kk][ty*4 + r]; b[r] = Bs[kk][tx*4 + r]; }
#pragma unroll
            for (int ar = 0; ar < 4; ++ar)
#pragma unroll
                for (int br = 0; br < 4; ++br)
                    acc[ar][br] = fmaf(a[ar], b[br], acc[ar][br]);
        }
        __syncthreads();
    }
#pragma unroll
    for (int ar = 0; ar < 4; ++ar) {
        const int row = m0 + ty*4 + ar;
        const int col = i0 + tx*4;
#pragma unroll
        for (int br = 0; br < 4; ++br) {
            float v = acc[ar][br] + lin_b[col + br];
            __bf16 h = (__bf16)v;
            lr_hi[(size_t)row * 512 + col + br] = h;
            lr_lo[(size_t)row * 512 + col + br] = (__bf16)(v - (float)h);
        }
    }
}

// ---------------------------------------------------------------------------
// Kernel 2b: split x -> x_hi/x_lo (bf16 [b][l][f]) + xT (bf16 [b][f][l])
// ---------------------------------------------------------------------------
__global__ __launch_bounds__(256) void split_x(const float* __restrict__ x,
                                               __bf16* __restrict__ x_hi,
                                               __bf16* __restrict__ x_lo,
                                               __bf16* __restrict__ xT) {
    const int b  = blockIdx.z;
    const int l0 = blockIdx.y * 64;
    const int f0 = blockIdx.x * 64;
    const int tid = threadIdx.x;
    __shared__ __bf16 tile[64][65];
    const int j = tid & 63;
#pragma unroll
    for (int s = 0; s < 16; ++s) {
        const int rr = (tid >> 6) + s * 4;
        const size_t o = ((size_t)(b * 512 + l0 + rr)) * 512 + f0 + j;
        float v = x[o];
        __bf16 h = (__bf16)v;
        x_hi[o] = h;
        x_lo[o] = (__bf16)(v - (float)h);
        tile[rr][j] = h;
    }
    __syncthreads();
#pragma unroll
    for (int s = 0; s < 16; ++s) {
        const int ff = (tid >> 6) + s * 4;
        xT[((size_t)(b * 512 + f0 + ff)) * 512 + l0 + j] = tile[j][ff];
    }
}

// ---------------------------------------------------------------------------
// Kernel 3: MFMA flash attention (unchanged from round 2, verified).
// ---------------------------------------------------------------------------
#define LT 64

__global__ __launch_bounds__(256) void attention_mfma(const __bf16* __restrict__ x_hi,
                                                      const __bf16* __restrict__ x_lo,
                                                      const __bf16* __restrict__ xT,
                                                      const __bf16* __restrict__ lr_hi,
                                                      const __bf16* __restrict__ lr_lo,
                                                      float* __restrict__ out) {
    const int b  = blockIdx.y;
    const int n0 = blockIdx.x * 16;
    const int tid  = threadIdx.x;
    const int wave = tid >> 6;
    const int lane = tid & 63;
    const int quad = lane >> 4;
    const int l16  = lane & 15;

    __shared__ float m_run[16];
    __shared__ float d_run[16];
    __shared__ float wavemax[4][16];
    __shared__ float wavesum[4][16];
    __shared__ float Ps[16][LT + 4];

    if (tid < 16) { m_run[tid] = -INFINITY; d_run[tid] = 0.f; }
    __syncthreads();

    f32x4 oacc[8];
#pragma unroll
    for (int fs = 0; fs < 8; ++fs) oacc[fs] = (f32x4){0.f, 0.f, 0.f, 0.f};

    const __bf16* lrh = lr_hi + (size_t)(n0 + l16) * FEAT + quad * 8;
    const __bf16* lrl = lr_lo + (size_t)(n0 + l16) * FEAT + quad * 8;

    for (int lt = 0; lt < LL; lt += LT) {
        const int lbase = lt + wave * 16;
        f32x4 s = (f32x4){0.f, 0.f, 0.f, 0.f};
        const __bf16* xh = x_hi + ((size_t)(b * LL + lbase + l16)) * FEAT + quad * 8;
        const __bf16* xl = x_lo + ((size_t)(b * LL + lbase + l16)) * FEAT + quad * 8;
#pragma unroll
        for (int k0 = 0; k0 < FEAT; k0 += 32) {
            const bf16x8 ah = *(const bf16x8*)(lrh + k0);
            const bf16x8 al = *(const bf16x8*)(lrl + k0);
            const bf16x8 bh = *(const bf16x8*)(xh + k0);
            const bf16x8 bl = *(const bf16x8*)(xl + k0);
            s = __builtin_amdgcn_mfma_f32_16x16x32_bf16(ah, bh, s, 0, 0, 0);
            s = __builtin_amdgcn_mfma_f32_16x16x32_bf16(ah, bl, s, 0, 0, 0);
            s = __builtin_amdgcn_mfma_f32_16x16x32_bf16(al, bh, s, 0, 0, 0);
        }
        float rmax[4];
#pragma unroll
        for (int r = 0; r < 4; ++r) {
            float v = s[r];
            v = fmaxf(v, __shfl_xor(v, 1));
            v = fmaxf(v, __shfl_xor(v, 2));
            v = fmaxf(v, __shfl_xor(v, 4));
            v = fmaxf(v, __shfl_xor(v, 8));
            rmax[r] = v;
        }
        if (l16 == 0) {
#pragma unroll
            for (int r = 0; r < 4; ++r) wavemax[wave][quad * 4 + r] = rmax[r];
        }
        __syncthreads();
        float mnew[4], alpha[4], p[4];
#pragma unroll
        for (int r = 0; r < 4; ++r) {
            const int n = quad * 4 + r;
            float tm = fmaxf(fmaxf(wavemax[0][n], wavemax[1][n]),
                             fmaxf(wavemax[2][n], wavemax[3][n]));
            float mo = m_run[n];
            mnew[r]  = fmaxf(mo, tm);
            alpha[r] = __expf(mo - mnew[r]);
            p[r]     = __expf(s[r] - mnew[r]);
            float ps = p[r];
            ps += __shfl_xor(ps, 1);
            ps += __shfl_xor(ps, 2);
            ps += __shfl_xor(ps, 4);
            ps += __shfl_xor(ps, 8);
            if (l16 == 0) wavesum[wave][n] = ps;
            Ps[n][wave * 16 + l16] = p[r];
        }
        __syncthreads();
        if (wave == 0 && l16 == 0) {
#pragma unroll
            for (int r = 0; r < 4; ++r) {
                const int n = quad * 4 + r;
                float sum4 = wavesum[0][n] + wavesum[1][n] + wavesum[2][n] + wavesum[3][n];
                d_run[n] = d_run[n] * alpha[r] + sum4;
                m_run[n] = mnew[r];
            }
        }
        __syncthreads();
#pragma unroll
        for (int fs = 0; fs < 8; ++fs)
#pragma unroll
            for (int r = 0; r < 4; ++r) oacc[fs][r] *= alpha[r];

        bf16x8 ap[2];
#pragma unroll
        for (int kb = 0; kb < 2; ++kb) {
            const float* srcp = &Ps[l16][kb * 32 + quad * 8];
            const float4 v0 = *(const float4*)(srcp);
            const float4 v1 = *(const float4*)(srcp + 4);
            bf16x8 t;
            t[0] = (__bf16)v0.x; t[1] = (__bf16)v0.y; t[2] = (__bf16)v0.z; t[3] = (__bf16)v0.w;
            t[4] = (__bf16)v1.x; t[5] = (__bf16)v1.y; t[6] = (__bf16)v1.z; t[7] = (__bf16)v1.w;
            ap[kb] = t;
        }
        const __bf16* xtb = xT + ((size_t)(b * FEAT + wave * 128 + l16)) * LL + lt + quad * 8;
#pragma unroll
        for (int fs = 0; fs < 8; ++fs) {
#pragma unroll
            for (int kb = 0; kb < 2; ++kb) {
                const bf16x8 bfrag = *(const bf16x8*)(xtb + (size_t)fs * 16 * LL + kb * 32);
                oacc[fs] = __builtin_amdgcn_mfma_f32_16x16x32_bf16(ap[kb], bfrag, oacc[fs], 0, 0, 0);
            }
        }
    }
    float dinv[4];
#pragma unroll
    for (int r = 0; r < 4; ++r) dinv[r] = 1.0f / d_run[quad * 4 + r];
#pragma unroll
    for (int fs = 0; fs < 8; ++fs) {
#pragma unroll
        for (int r = 0; r < 4; ++r) {
            const int n = n0 + quad * 4 + r;
            const int f = wave * 128 + fs * 16 + l16;
            out[((size_t)(b * NLAB + n)) * FEAT + f] = oacc[fs][r] * dinv[r];
        }
    }
}

// ---------------------------------------------------------------------------
// Workspace layout (float-slot offsets), peak 32 MB:
//   [0        .. 1048576)  lr_hi   (4096*512 bf16)
//   [1048576  .. 2097152)  lr_lo
//   [2097152  .. 2424832)  wBt_hi  (16*128*320 bf16, dead after conv_mfma)
//   [2424832  .. 2752512)  wBt_lo  (dead after conv_mfma)
//   [2752512  .. 4849664)  lr0     (fp32, dead after linear_kernel)
//   [2097152  .. 4194304)  x_hi    (written by split_x, after linear)
//   [4194304  .. 6291456)  x_lo
//   [6291456  .. 8388608)  xT
// ---------------------------------------------------------------------------
extern "C" void kernel_launch(void* const* d_in, const int* in_sizes, int n_in,
                              void* d_out, int out_size, void* d_ws, size_t ws_size,
                              hipStream_t stream) {
    const float* x          = (const float*)d_in[0];  // (16,512,512)
    const float* label_reps = (const float*)d_in[1];  // (4096,32,300)
    const float* conv_w     = (const float*)d_in[2];  // (512,300,4)
    const float* conv_b     = (const float*)d_in[3];  // (512,)
    const float* lin_w      = (const float*)d_in[4];  // (512,512)
    const float* lin_b      = (const float*)d_in[5];  // (512,)
    float* out = (float*)d_out;

    float* wsf = (float*)d_ws;
    __bf16* lr_hi  = (__bf16*)(wsf);
    __bf16* lr_lo  = (__bf16*)(wsf + 1048576);
    __bf16* wBt_hi = (__bf16*)(wsf + 2097152);
    __bf16* wBt_lo = (__bf16*)(wsf + 2424832);
    float*  lr0    = wsf + 2752512;
    __bf16* x_hi   = (__bf16*)(wsf + 2097152);   // aliases wBt/lr0 (dead by then)
    __bf16* x_lo   = (__bf16*)(wsf + 4194304);
    __bf16* xT     = (__bf16*)(wsf + 6291456);

    wprep<<<dim3(2048), dim3(256), 0, stream>>>(conv_w, wBt_hi, wBt_lo);
    conv_mfma<<<dim3(16, 1024), dim3(256), 0, stream>>>(label_reps, wBt_hi, wBt_lo, conv_b, lr0);
    linear_kernel<<<dim3(64, 8), dim3(256), 0, stream>>>(lr0, lin_w, lin_b, lr_hi, lr_lo);
    split_x<<<dim3(8, 8, 16), dim3(256), 0, stream>>>(x, x_hi, x_lo, xT);
    attention_mfma<<<dim3(NLAB / 16, BB), dim3(256), 0, stream>>>(x_hi, x_lo, xT, lr_hi, lr_lo, out);
}